// Round 2
// baseline (192.424 us; speedup 1.0000x reference)
//
#include <hip/hip_runtime.h>

typedef unsigned short u16;
typedef __bf16 bf16x8 __attribute__((ext_vector_type(8)));
typedef float f32x4 __attribute__((ext_vector_type(4)));

__device__ inline u16 f2bf(float f) {
    union { float f; unsigned int u; } a; a.f = f;
    unsigned int u = a.u + 0x7fffu + ((a.u >> 16) & 1u);
    return (u16)(u >> 16);
}

// async global->LDS, 16B per lane. LDS side is wave-uniform base + lane*16.
__device__ __forceinline__ void cp16(const void* g, void* l) {
    __builtin_amdgcn_global_load_lds(
        (const __attribute__((address_space(1))) unsigned int*)g,
        (__attribute__((address_space(3))) unsigned int*)l, 16, 0, 0);
}

// -------- prep: fuse x-cast + both weight transposes (1 launch) --------
__global__ __launch_bounds__(256) void prep(
    const float* __restrict__ x, const float* __restrict__ wq,
    const float* __restrict__ wo, u16* __restrict__ xbf,
    u16* __restrict__ wtq, u16* __restrict__ wto)
{
    int bid = blockIdx.x;
    if (bid < 3072) {                      // cast x: f32 -> bf16, 8/thread
        size_t base = ((size_t)bid * 256 + threadIdx.x) * 8;
        float4 f0 = *(const float4*)&x[base];
        float4 f1 = *(const float4*)&x[base + 4];
        union { u16 s[8]; uint4 v; } t;
        t.s[0]=f2bf(f0.x); t.s[1]=f2bf(f0.y); t.s[2]=f2bf(f0.z); t.s[3]=f2bf(f0.w);
        t.s[4]=f2bf(f1.x); t.s[5]=f2bf(f1.y); t.s[6]=f2bf(f1.z); t.s[7]=f2bf(f1.w);
        *(uint4*)&xbf[base] = t.v;
        return;
    }
    __shared__ u16 tile[32][33];
    const float* in; u16* outp; int N, bx, by;
    if (bid < 3072 + 1728) { int t = bid - 3072; in = wq; outp = wtq; N = 2304; bx = t % 72; by = t / 72; }
    else                   { int t = bid - 4800; in = wo; outp = wto; N = 768;  bx = t % 24; by = t / 24; }
    int n0 = bx * 32, k0 = by * 32;
    int tx = threadIdx.x & 31, ty = threadIdx.x >> 5;
    #pragma unroll
    for (int r = ty; r < 32; r += 8)
        tile[r][tx] = f2bf(in[(size_t)(k0 + r) * N + n0 + tx]);
    __syncthreads();
    #pragma unroll
    for (int r = ty; r < 32; r += 8)
        outp[(size_t)(n0 + r) * 768 + k0 + tx] = tile[tx][r];
}

// -------- QKV GEMM: BK=64, dbuf, counted-vmcnt pipeline (T4), XCD-pinned --------
// A bf16 [8192][768], Bt bf16 [2304][768]
// Q (*0.125*log2e) -> [b,h,n,64]; K -> [b,h,n,64]; V -> TRANSPOSED [b,h,d,n]
__global__ __launch_bounds__(256) void gemm_qkv(
    const u16* __restrict__ A, const u16* __restrict__ Bt,
    u16* __restrict__ q_out, u16* __restrict__ k_out, u16* __restrict__ v_out)
{
    const int K = 768;
    __shared__ __align__(16) u16 As[2][128 * 64];   // slot s of row R holds k-group s^(R&7)
    __shared__ __align__(16) u16 Bs[2][128 * 64];

    int tid = threadIdx.x;
    int lane = tid & 63, wave = tid >> 6;
    int quad = lane >> 4, l16 = lane & 15;
    int wm = wave >> 1, wn = wave & 1;
    int id = blockIdx.x;
    int xcd = id & 7, j = id >> 3;
    int m0 = (((j & 7) << 3) + xcd) * 128;   // 64 m-tiles, XCD-pinned A slabs
    int n0 = (j >> 3) * 128;                 // 18 n-tiles

    f32x4 acc[4][4];
    #pragma unroll
    for (int i = 0; i < 4; i++)
        #pragma unroll
        for (int jj = 0; jj < 4; jj++) acc[i][jj] = (f32x4){0.f, 0.f, 0.f, 0.f};

    int r0 = tid >> 3, cg = tid & 7;
    int g = cg ^ (r0 & 7);                   // row&7 == r0&7 for all 4 its
    const u16* GA[4]; const u16* GB[4];
    #pragma unroll
    for (int it = 0; it < 4; it++) {
        GA[it] = A  + (size_t)(m0 + it * 32 + r0) * K + g * 8;
        GB[it] = Bt + (size_t)(n0 + it * 32 + r0) * K + g * 8;
    }

    #define STAGE_QKV(kt, b)                                          \
        _Pragma("unroll")                                             \
        for (int it = 0; it < 4; it++) {                              \
            cp16(GA[it] + (kt), &As[b][(it * 256 + tid) * 8]);        \
            cp16(GB[it] + (kt), &Bs[b][(it * 256 + tid) * 8]);        \
        }

    STAGE_QKV(0, 0)
    for (int i = 0; i < 12; i++) {
        int b = i & 1;
        // T4: issue next tile's loads FIRST, then wait only for tile i's 8 loads.
        if (i + 1 < 12) {
            STAGE_QKV((i + 1) * 64, b ^ 1)
            asm volatile("s_waitcnt vmcnt(8)" ::: "memory");
        } else {
            asm volatile("s_waitcnt vmcnt(0)" ::: "memory");
        }
        __builtin_amdgcn_s_barrier();        // all waves: tile i resident in buf b
        bf16x8 af[2][4], bfr[2][4];
        #pragma unroll
        for (int ko = 0; ko < 2; ko++)
            #pragma unroll
            for (int x = 0; x < 4; x++) {
                int Ra = wm * 64 + x * 16 + l16;
                af[ko][x]  = *(const bf16x8*)&As[b][Ra * 64 + (((ko * 4 + quad) ^ (Ra & 7)) * 8)];
                int Rb = wn * 64 + x * 16 + l16;
                bfr[ko][x] = *(const bf16x8*)&Bs[b][Rb * 64 + (((ko * 4 + quad) ^ (Rb & 7)) * 8)];
            }
        #pragma unroll
        for (int ko = 0; ko < 2; ko++)
            #pragma unroll
            for (int x = 0; x < 4; x++)
                #pragma unroll
                for (int y = 0; y < 4; y++)
                    acc[x][y] = __builtin_amdgcn_mfma_f32_16x16x32_bf16(af[ko][x], bfr[ko][y], acc[x][y], 0, 0, 0);
        __builtin_amdgcn_s_barrier();        // WAR: buf b fully read before iter i+1 overwrites it
    }
    #undef STAGE_QKV

    // ---- epilogue: wave tile = 64m x 64n, one (part,h); per-wave LDS region in buf0 ----
    int M0 = m0 + wm * 64, N0 = n0 + wn * 64;
    int part = N0 >= 1536 ? 2 : (N0 >= 768 ? 1 : 0);
    int h = (N0 - part * 768) >> 6;
    int b2 = M0 >> 10, npos0 = M0 & 1023;
    u16* ep = (wave < 2 ? As[0] : Bs[0]) + (wave & 1) * 4096;   // 8 KB per wave (buf0: free)

    if (part != 2) {
        float scale = (part == 0) ? 0.18033688011112042f : 1.0f;   // /8 * log2e for Q
        u16* gbase = (part == 0 ? q_out : k_out) + (((size_t)(b2 * 12 + h) * 1024 + npos0) << 6);
        #pragma unroll
        for (int i = 0; i < 4; i++)
            #pragma unroll
            for (int jj = 0; jj < 4; jj++) {
                int dd = jj * 16 + l16;
                #pragma unroll
                for (int r = 0; r < 4; r++) {
                    int np = i * 16 + quad * 4 + r;
                    ep[np * 64 + (((dd >> 3) ^ (np & 7)) * 8) + (dd & 7)] =
                        f2bf(acc[i][jj][r] * scale);
                }
            }
        #pragma unroll
        for (int t = 0; t < 8; t++) {        // per-wave region: ds order suffices, no barrier
            int idx = t * 512 + lane * 8;
            int np = idx >> 6;
            int slot = ((lane & 7) ^ (np & 7));
            uint4 v = *(const uint4*)&ep[np * 64 + slot * 8];
            *(uint4*)&gbase[idx] = v;
        }
    } else {
        #pragma unroll
        for (int i = 0; i < 4; i++)
            #pragma unroll
            for (int jj = 0; jj < 4; jj++) {
                int dd = jj * 16 + l16;
                int npg = i * 2 + (quad >> 1);
                int sub = (quad & 1) * 4;
                union { u16 s[4]; uint2 v; } pk;
                #pragma unroll
                for (int r = 0; r < 4; r++) pk.s[r] = f2bf(acc[i][jj][r]);
                *(uint2*)&ep[dd * 64 + ((npg ^ (dd & 7)) * 8) + sub] = pk.v;
            }
        #pragma unroll
        for (int t = 0; t < 8; t++) {
            int dd = t * 8 + (lane >> 3);
            int npg = lane & 7;
            uint4 v = *(const uint4*)&ep[dd * 64 + ((npg ^ (dd & 7)) * 8)];
            *(uint4*)&v_out[((size_t)((b2 * 12 + h) * 64 + dd)) * 1024 + npos0 + npg * 8] = v;
        }
    }
}

// -------- attention: S^T form, 128 q/block, reg-staged V w/ 8B-chunk swizzle, l via MFMA --------
// Vs layout: row d (128B) as 16 x 8B chunks; global chunk c stored at position c ^ (d&15).
// => every quarter-wave V-read covers all 32 banks: conflict-free (was 4 cyc/read conflicts).
__global__ __launch_bounds__(256) void attn128(
    u16* __restrict__ QO, const u16* __restrict__ Kg, const u16* __restrict__ Vtg)
{
    __shared__ __align__(16) u16 Ks[2][64 * 64];   // [kv][d], 16B groups XOR-swizzled
    __shared__ __align__(16) u16 Vs[2][64 * 64];   // [d][kv], 8B chunks swizzled c^(d&15)

    int tid = threadIdx.x;
    int lane = tid & 63, wave = tid >> 6;
    int quad = lane >> 4, l16 = lane & 15;
    int id = blockIdx.x;
    int xcd = id & 7, j = id >> 3;              // 12 heads per XCD
    int bh = xcd * 12 + (j >> 3);
    int q0 = (j & 7) * 128;
    const size_t head_base = (size_t)bh * 65536;

    size_t qoff[2];
    bf16x8 qf[2][2];
    #pragma unroll
    for (int qs = 0; qs < 2; qs++) {
        qoff[qs] = head_base + (size_t)(q0 + wave * 32 + qs * 16 + l16) * 64;
        qf[qs][0] = *(const bf16x8*)&QO[qoff[qs] + quad * 8];
        qf[qs][1] = *(const bf16x8*)&QO[qoff[qs] + 32 + quad * 8];
    }

    f32x4 Oacc[4][2];
    #pragma unroll
    for (int dt = 0; dt < 4; dt++)
        #pragma unroll
        for (int qs = 0; qs < 2; qs++) Oacc[dt][qs] = (f32x4){0.f, 0.f, 0.f, 0.f};
    f32x4 lacc[2];
    lacc[0] = (f32x4){0.f, 0.f, 0.f, 0.f};
    lacc[1] = (f32x4){0.f, 0.f, 0.f, 0.f};

    // ones A-fragment for l = sum_k P[k][q] via MFMA
    union { unsigned int w[4]; bf16x8 v; } ones;
    ones.w[0] = ones.w[1] = ones.w[2] = ones.w[3] = 0x3f803f80u;

    int srow = tid >> 3, sg = tid & 7;
    // K: cp16 with 16B-group source pre-swizzle (unchanged)
    int gsK = sg ^ (srow & 7);
    const u16* GK[2];
    GK[0] = Kg + head_base + (size_t)(srow) * 64 + gsK * 8;
    GK[1] = Kg + head_base + (size_t)(32 + srow) * 64 + gsK * 8;
    // V: natural global source (reg-staged), rows are d, 1024-wide kv
    const u16* GV[2];
    GV[0] = Vtg + head_base + (size_t)(srow) * 1024 + sg * 8;
    GV[1] = Vtg + head_base + (size_t)(32 + srow) * 1024 + sg * 8;
    // V LDS write offsets (u16 units): row r, chunks 2sg and 2sg+1 at pos c^(r&15)
    int vwA[2], vwB[2];
    #pragma unroll
    for (int it = 0; it < 2; it++) {
        int r = it * 32 + srow;
        vwA[it] = r * 64 + (((2 * sg)     ^ (r & 15)) * 4);
        vwB[it] = r * 64 + (((2 * sg + 1) ^ (r & 15)) * 4);
    }

    // prologue: stage tile 0 (V-gloads first, then K-cp16s: vmcnt order matters)
    uint4 v0a = *(const uint4*)GV[0];
    uint4 v0b = *(const uint4*)GV[1];
    cp16(GK[0], &Ks[0][(0 * 256 + tid) * 8]);
    cp16(GK[1], &Ks[0][(1 * 256 + tid) * 8]);
    { uint2 t;
      t.x = v0a.x; t.y = v0a.y; *(uint2*)&Vs[0][vwA[0]] = t;
      t.x = v0a.z; t.y = v0a.w; *(uint2*)&Vs[0][vwB[0]] = t;
      t.x = v0b.x; t.y = v0b.y; *(uint2*)&Vs[0][vwA[1]] = t;
      t.x = v0b.z; t.y = v0b.w; *(uint2*)&Vs[0][vwB[1]] = t; }
    asm volatile("s_waitcnt lgkmcnt(0)" ::: "memory");

    for (int i = 0; i < 16; i++) {
        int b = i & 1;
        uint4 vna, vnb;
        if (i + 1 < 16) {
            // issue next V (regs) then next K (cp16); vmcnt(4) waits only K(i)'s 2 cp16s
            vna = *(const uint4*)(GV[0] + (i + 1) * 64);
            vnb = *(const uint4*)(GV[1] + (i + 1) * 64);
            cp16(GK[0] + (size_t)(i + 1) * 4096, &Ks[b ^ 1][(0 * 256 + tid) * 8]);
            cp16(GK[1] + (size_t)(i + 1) * 4096, &Ks[b ^ 1][(1 * 256 + tid) * 8]);
            asm volatile("s_waitcnt vmcnt(4)" ::: "memory");
        } else {
            asm volatile("s_waitcnt vmcnt(0)" ::: "memory");
        }
        __builtin_amdgcn_s_barrier();         // K(i) in LDS; V(i) ds_writes drained last iter

        // ---- QK^T ----
        bf16x8 kf[4][2];
        #pragma unroll
        for (int nt = 0; nt < 4; nt++) {
            int R = nt * 16 + l16;
            kf[nt][0] = *(const bf16x8*)&Ks[b][R * 64 + ((quad       ^ (R & 7)) * 8)];
            kf[nt][1] = *(const bf16x8*)&Ks[b][R * 64 + (((quad + 4) ^ (R & 7)) * 8)];
        }
        f32x4 s4[4][2];
        #pragma unroll
        for (int nt = 0; nt < 4; nt++)
            #pragma unroll
            for (int qs = 0; qs < 2; qs++) {
                f32x4 s = (f32x4){0.f, 0.f, 0.f, 0.f};
                s = __builtin_amdgcn_mfma_f32_16x16x32_bf16(kf[nt][0], qf[qs][0], s, 0, 0, 0);
                s = __builtin_amdgcn_mfma_f32_16x16x32_bf16(kf[nt][1], qf[qs][1], s, 0, 0, 0);
                s4[nt][qs] = s;
            }

        // p = 2^s (f32, packed to bf16 via cvt_pk below; l accumulated via ones-MFMA)
        float p[4][2][4];
        #pragma unroll
        for (int nt = 0; nt < 4; nt++)
            #pragma unroll
            for (int qs = 0; qs < 2; qs++)
                #pragma unroll
                for (int r = 0; r < 4; r++)
                    p[nt][qs][r] = __builtin_amdgcn_exp2f(s4[nt][qs][r]);

        // write V(i+1) into Vs[b^1] (T14 late-write; K(i+1) cp16s stay in flight)
        if (i + 1 < 16) {
            asm volatile("s_waitcnt vmcnt(2)" ::: "memory");
            uint2 t;
            t.x = vna.x; t.y = vna.y; *(uint2*)&Vs[b ^ 1][vwA[0]] = t;
            t.x = vna.z; t.y = vna.w; *(uint2*)&Vs[b ^ 1][vwB[0]] = t;
            t.x = vnb.x; t.y = vnb.y; *(uint2*)&Vs[b ^ 1][vwA[1]] = t;
            t.x = vnb.z; t.y = vnb.w; *(uint2*)&Vs[b ^ 1][vwB[1]] = t;
        }

        // ---- PV ----
        __builtin_amdgcn_s_setprio(1);
        #pragma unroll
        for (int h = 0; h < 2; h++) {
            union { unsigned int w[4]; bf16x8 v; } pk[2];
            #pragma unroll
            for (int qs = 0; qs < 2; qs++) {
                asm("v_cvt_pk_bf16_f32 %0, %1, %2" : "=v"(pk[qs].w[0]) : "v"(p[2*h][qs][0]),     "v"(p[2*h][qs][1]));
                asm("v_cvt_pk_bf16_f32 %0, %1, %2" : "=v"(pk[qs].w[1]) : "v"(p[2*h][qs][2]),     "v"(p[2*h][qs][3]));
                asm("v_cvt_pk_bf16_f32 %0, %1, %2" : "=v"(pk[qs].w[2]) : "v"(p[2*h+1][qs][0]),   "v"(p[2*h+1][qs][1]));
                asm("v_cvt_pk_bf16_f32 %0, %1, %2" : "=v"(pk[qs].w[3]) : "v"(p[2*h+1][qs][2]),   "v"(p[2*h+1][qs][3]));
                lacc[qs] = __builtin_amdgcn_mfma_f32_16x16x32_bf16(ones.v, pk[qs].v, lacc[qs], 0, 0, 0);
            }
            int pbase = ((8 * h + quad) ^ l16) * 4;    // chunk (8h+quad) at pos ^l16, u16 idx
            #pragma unroll
            for (int dt = 0; dt < 4; dt++) {
                int drow = dt * 16 + l16;
                union { u16 s[8]; bf16x8 v; } vk;
                *(uint2*)&vk.s[0] = *(const uint2*)&Vs[b][drow * 64 + pbase];
                *(uint2*)&vk.s[4] = *(const uint2*)&Vs[b][drow * 64 + (pbase ^ 16)]; // chunk +4
                #pragma unroll
                for (int qs = 0; qs < 2; qs++)
                    Oacc[dt][qs] = __builtin_amdgcn_mfma_f32_16x16x32_bf16(vk.v, pk[qs].v, Oacc[dt][qs], 0, 0, 0);
            }
        }
        __builtin_amdgcn_s_setprio(0);

        asm volatile("s_waitcnt lgkmcnt(0)" ::: "memory");  // drain V ds_writes (+reads)
        __builtin_amdgcn_s_barrier();         // WAR: buf b fully read before overwrite
    }

    #pragma unroll
    for (int qs = 0; qs < 2; qs++) {
        float rl = __builtin_amdgcn_rcpf(lacc[qs][0]);   // l[q=l16], replicated in all regs
        #pragma unroll
        for (int dt = 0; dt < 4; dt++) {
            union { u16 s[4]; uint2 v; } ok;
            #pragma unroll
            for (int r = 0; r < 4; r++) ok.s[r] = f2bf(Oacc[dt][qs][r] * rl);
            *(uint2*)&QO[qoff[qs] + dt * 16 + quad * 4] = ok.v;
        }
    }
}

// -------- out-proj GEMM: BK=64, dbuf, counted-vmcnt pipeline, XCD-pinned --------
__global__ __launch_bounds__(256) void gemm_out(
    const u16* __restrict__ Qg, const u16* __restrict__ Bt,
    const float* __restrict__ bias, float* __restrict__ out)
{
    const int K = 768;
    __shared__ __align__(16) u16 As[2][128 * 64];
    __shared__ __align__(16) u16 Bs[2][128 * 64];

    int tid = threadIdx.x;
    int lane = tid & 63, wave = tid >> 6;
    int quad = lane >> 4, l16 = lane & 15;
    int wm = wave >> 1, wn = wave & 1;
    int id = blockIdx.x;
    int xcd = id & 7, j = id >> 3;
    int m0 = (((j & 7) << 3) + xcd) * 128;
    int n0 = (j >> 3) * 128;

    f32x4 acc[4][4];
    #pragma unroll
    for (int i = 0; i < 4; i++)
        #pragma unroll
        for (int jj = 0; jj < 4; jj++) acc[i][jj] = (f32x4){0.f, 0.f, 0.f, 0.f};

    int r0 = tid >> 3, cg = tid & 7;
    int g = cg ^ (r0 & 7);
    const u16* GA[4]; const u16* GB[4];
    #pragma unroll
    for (int it = 0; it < 4; it++) {
        int m = m0 + it * 32 + r0, b = m >> 10, npos = m & 1023;
        GA[it] = Qg + (((size_t)(b * 12) * 1024 + npos) << 6) + g * 8;  // + h*65536
        GB[it] = Bt + (size_t)(n0 + it * 32 + r0) * K + g * 8;          // + kt
    }

    #define STAGE_OUT(i2, b)                                              \
        _Pragma("unroll")                                                 \
        for (int it = 0; it < 4; it++) {                                  \
            cp16(GA[it] + (size_t)(i2) * 65536, &As[b][(it * 256 + tid) * 8]); \
            cp16(GB[it] + (i2) * 64,            &Bs[b][(it * 256 + tid) * 8]); \
        }

    STAGE_OUT(0, 0)
    for (int i = 0; i < 12; i++) {
        int b = i & 1;
        if (i + 1 < 12) {
            STAGE_OUT(i + 1, b ^ 1)
            asm volatile("s_waitcnt vmcnt(8)" ::: "memory");
        } else {
            asm volatile("s_waitcnt vmcnt(0)" ::: "memory");
        }
        __builtin_amdgcn_s_barrier();
        bf16x8 af[2][4], bfr[2][4];
        #pragma unroll
        for (int ko = 0; ko < 2; ko++)
            #pragma unroll
            for (int x = 0; x < 4; x++) {
                int Ra = wm * 64 + x * 16 + l16;
                af[ko][x]  = *(const bf16x8*)&As[b][Ra * 64 + (((ko * 4 + quad) ^ (Ra & 7)) * 8)];
                int Rb = wn * 64 + x * 16 + l16;
                bfr[ko][x] = *(const bf16x8*)&Bs[b][Rb * 64 + (((ko * 4 + quad) ^ (Rb & 7)) * 8)];
            }
        #pragma unroll
        for (int ko = 0; ko < 2; ko++)
            #pragma unroll
            for (int x = 0; x < 4; x++)
                #pragma unroll
                for (int y = 0; y < 4; y++)
                    acc[x][y] = __builtin_amdgcn_mfma_f32_16x16x32_bf16(af[ko][x], bfr[ko][y], acc[x][y], 0, 0, 0);
        __builtin_amdgcn_s_barrier();
    }
    #undef STAGE_OUT

    #pragma unroll
    for (int i = 0; i < 4; i++) {
        int mbase = m0 + wm * 64 + i * 16 + quad * 4;
        #pragma unroll
        for (int jj = 0; jj < 4; jj++) {
            int n = n0 + wn * 64 + jj * 16 + l16;
            float bv = bias[n];
            #pragma unroll
            for (int r = 0; r < 4; r++)
                out[(size_t)(mbase + r) * 768 + n] = acc[i][jj][r] + bv;
        }
    }
}

extern "C" void kernel_launch(void* const* d_in, const int* in_sizes, int n_in,
                              void* d_out, int out_size, void* d_ws, size_t ws_size,
                              hipStream_t stream) {
    const float* x     = (const float*)d_in[0];   // [8,1024,768] f32
    const float* w_qkv = (const float*)d_in[1];   // [768,2304] f32
    const float* w_out = (const float*)d_in[2];   // [768,768] f32
    const float* b_out = (const float*)d_in[3];   // [768] f32
    float* out = (float*)d_out;                   // [8,1024,768] f32

    char* ws = (char*)d_ws;
    u16* wtq  = (u16*)(ws);                   // [2304][768] bf16    3,538,944 B
    u16* wto  = (u16*)(ws + 3538944);         // [768][768]  bf16    1,179,648 B
    u16* Qbuf = (u16*)(ws + 4718592);         // [8,12,1024,64] bf16 12,582,912 B
    u16* xbf  = (u16*)(ws + 17301504);        // [8192][768] bf16    12,582,912 B  (29.9 MB)
    // K natural [b,h,n,64] and V TRANSPOSED [b,h,64,n] live in d_out (2x12.58 MB);
    // both fully consumed by attn128 before gemm_out overwrites d_out.
    u16* Kbuf = (u16*)d_out;
    u16* Vbuf = (u16*)d_out + 6291456;

    prep<<<dim3(5376), 256, 0, stream>>>(x, w_qkv, w_out, xbf, wtq, wto);
    gemm_qkv<<<dim3(1152), 256, 0, stream>>>(xbf, wtq, Qbuf, Kbuf, Vbuf);
    attn128<<<dim3(768), 256, 0, stream>>>(Qbuf, Kbuf, Vbuf);
    gemm_out<<<dim3(384), 256, 0, stream>>>(Qbuf, wto, b_out, out);
}

// Round 3
// 187.667 us; speedup vs baseline: 1.0253x; 1.0253x over previous
//
#include <hip/hip_runtime.h>

typedef unsigned short u16;
typedef __bf16 bf16x8 __attribute__((ext_vector_type(8)));
typedef float f32x4 __attribute__((ext_vector_type(4)));

__device__ inline u16 f2bf(float f) {
    union { float f; unsigned int u; } a; a.f = f;
    unsigned int u = a.u + 0x7fffu + ((a.u >> 16) & 1u);
    return (u16)(u >> 16);
}

// async global->LDS, 16B per lane. LDS side is wave-uniform base + lane*16.
__device__ __forceinline__ void cp16(const void* g, void* l) {
    __builtin_amdgcn_global_load_lds(
        (const __attribute__((address_space(1))) unsigned int*)g,
        (__attribute__((address_space(3))) unsigned int*)l, 16, 0, 0);
}

// -------- prep: fuse x-cast + both weight transposes (1 launch) --------
__global__ __launch_bounds__(256) void prep(
    const float* __restrict__ x, const float* __restrict__ wq,
    const float* __restrict__ wo, u16* __restrict__ xbf,
    u16* __restrict__ wtq, u16* __restrict__ wto)
{
    int bid = blockIdx.x;
    if (bid < 3072) {                      // cast x: f32 -> bf16, 8/thread
        size_t base = ((size_t)bid * 256 + threadIdx.x) * 8;
        float4 f0 = *(const float4*)&x[base];
        float4 f1 = *(const float4*)&x[base + 4];
        union { u16 s[8]; uint4 v; } t;
        t.s[0]=f2bf(f0.x); t.s[1]=f2bf(f0.y); t.s[2]=f2bf(f0.z); t.s[3]=f2bf(f0.w);
        t.s[4]=f2bf(f1.x); t.s[5]=f2bf(f1.y); t.s[6]=f2bf(f1.z); t.s[7]=f2bf(f1.w);
        *(uint4*)&xbf[base] = t.v;
        return;
    }
    __shared__ u16 tile[32][33];
    const float* in; u16* outp; int N, bx, by;
    if (bid < 3072 + 1728) { int t = bid - 3072; in = wq; outp = wtq; N = 2304; bx = t % 72; by = t / 72; }
    else                   { int t = bid - 4800; in = wo; outp = wto; N = 768;  bx = t % 24; by = t / 24; }
    int n0 = bx * 32, k0 = by * 32;
    int tx = threadIdx.x & 31, ty = threadIdx.x >> 5;
    #pragma unroll
    for (int r = ty; r < 32; r += 8)
        tile[r][tx] = f2bf(in[(size_t)(k0 + r) * N + n0 + tx]);
    __syncthreads();
    #pragma unroll
    for (int r = ty; r < 32; r += 8)
        outp[(size_t)(n0 + r) * 768 + k0 + tx] = tile[tx][r];
}

// -------- QKV GEMM: BK=64, dbuf, counted-vmcnt pipeline (T4), XCD-pinned --------
// A bf16 [8192][768], Bt bf16 [2304][768]
// Q (*0.125*log2e) -> [b,h,n,64]; K -> [b,h,n,64]; V -> TRANSPOSED [b,h,d,n]
__global__ __launch_bounds__(256) void gemm_qkv(
    const u16* __restrict__ A, const u16* __restrict__ Bt,
    u16* __restrict__ q_out, u16* __restrict__ k_out, u16* __restrict__ v_out)
{
    const int K = 768;
    __shared__ __align__(16) u16 As[2][128 * 64];   // slot s of row R holds k-group s^(R&7)
    __shared__ __align__(16) u16 Bs[2][128 * 64];

    int tid = threadIdx.x;
    int lane = tid & 63, wave = tid >> 6;
    int quad = lane >> 4, l16 = lane & 15;
    int wm = wave >> 1, wn = wave & 1;
    int id = blockIdx.x;
    int xcd = id & 7, j = id >> 3;
    int m0 = (((j & 7) << 3) + xcd) * 128;   // 64 m-tiles, XCD-pinned A slabs
    int n0 = (j >> 3) * 128;                 // 18 n-tiles

    f32x4 acc[4][4];
    #pragma unroll
    for (int i = 0; i < 4; i++)
        #pragma unroll
        for (int jj = 0; jj < 4; jj++) acc[i][jj] = (f32x4){0.f, 0.f, 0.f, 0.f};

    int r0 = tid >> 3, cg = tid & 7;
    int g = cg ^ (r0 & 7);                   // row&7 == r0&7 for all 4 its
    const u16* GA[4]; const u16* GB[4];
    #pragma unroll
    for (int it = 0; it < 4; it++) {
        GA[it] = A  + (size_t)(m0 + it * 32 + r0) * K + g * 8;
        GB[it] = Bt + (size_t)(n0 + it * 32 + r0) * K + g * 8;
    }

    #define STAGE_QKV(kt, b)                                          \
        _Pragma("unroll")                                             \
        for (int it = 0; it < 4; it++) {                              \
            cp16(GA[it] + (kt), &As[b][(it * 256 + tid) * 8]);        \
            cp16(GB[it] + (kt), &Bs[b][(it * 256 + tid) * 8]);        \
        }

    STAGE_QKV(0, 0)
    for (int i = 0; i < 12; i++) {
        int b = i & 1;
        // T4: issue next tile's loads FIRST, then wait only for tile i's 8 loads.
        if (i + 1 < 12) {
            STAGE_QKV((i + 1) * 64, b ^ 1)
            asm volatile("s_waitcnt vmcnt(8)" ::: "memory");
        } else {
            asm volatile("s_waitcnt vmcnt(0)" ::: "memory");
        }
        __builtin_amdgcn_s_barrier();        // all waves: tile i resident in buf b
        bf16x8 af[2][4], bfr[2][4];
        #pragma unroll
        for (int ko = 0; ko < 2; ko++)
            #pragma unroll
            for (int x = 0; x < 4; x++) {
                int Ra = wm * 64 + x * 16 + l16;
                af[ko][x]  = *(const bf16x8*)&As[b][Ra * 64 + (((ko * 4 + quad) ^ (Ra & 7)) * 8)];
                int Rb = wn * 64 + x * 16 + l16;
                bfr[ko][x] = *(const bf16x8*)&Bs[b][Rb * 64 + (((ko * 4 + quad) ^ (Rb & 7)) * 8)];
            }
        #pragma unroll
        for (int ko = 0; ko < 2; ko++)
            #pragma unroll
            for (int x = 0; x < 4; x++)
                #pragma unroll
                for (int y = 0; y < 4; y++)
                    acc[x][y] = __builtin_amdgcn_mfma_f32_16x16x32_bf16(af[ko][x], bfr[ko][y], acc[x][y], 0, 0, 0);
        __builtin_amdgcn_s_barrier();        // WAR: buf b fully read before iter i+1 overwrites it
    }
    #undef STAGE_QKV

    // ---- epilogue: wave tile = 64m x 64n, one (part,h); per-wave LDS region in buf0 ----
    int M0 = m0 + wm * 64, N0 = n0 + wn * 64;
    int part = N0 >= 1536 ? 2 : (N0 >= 768 ? 1 : 0);
    int h = (N0 - part * 768) >> 6;
    int b2 = M0 >> 10, npos0 = M0 & 1023;
    u16* ep = (wave < 2 ? As[0] : Bs[0]) + (wave & 1) * 4096;   // 8 KB per wave (buf0: free)

    if (part != 2) {
        float scale = (part == 0) ? 0.18033688011112042f : 1.0f;   // /8 * log2e for Q
        u16* gbase = (part == 0 ? q_out : k_out) + (((size_t)(b2 * 12 + h) * 1024 + npos0) << 6);
        #pragma unroll
        for (int i = 0; i < 4; i++)
            #pragma unroll
            for (int jj = 0; jj < 4; jj++) {
                int dd = jj * 16 + l16;
                #pragma unroll
                for (int r = 0; r < 4; r++) {
                    int np = i * 16 + quad * 4 + r;
                    ep[np * 64 + (((dd >> 3) ^ (np & 7)) * 8) + (dd & 7)] =
                        f2bf(acc[i][jj][r] * scale);
                }
            }
        #pragma unroll
        for (int t = 0; t < 8; t++) {        // per-wave region: ds order suffices, no barrier
            int idx = t * 512 + lane * 8;
            int np = idx >> 6;
            int slot = ((lane & 7) ^ (np & 7));
            uint4 v = *(const uint4*)&ep[np * 64 + slot * 8];
            *(uint4*)&gbase[idx] = v;
        }
    } else {
        #pragma unroll
        for (int i = 0; i < 4; i++)
            #pragma unroll
            for (int jj = 0; jj < 4; jj++) {
                int dd = jj * 16 + l16;
                int npg = i * 2 + (quad >> 1);
                int sub = (quad & 1) * 4;
                union { u16 s[4]; uint2 v; } pk;
                #pragma unroll
                for (int r = 0; r < 4; r++) pk.s[r] = f2bf(acc[i][jj][r]);
                *(uint2*)&ep[dd * 64 + ((npg ^ (dd & 7)) * 8) + sub] = pk.v;
            }
        #pragma unroll
        for (int t = 0; t < 8; t++) {
            int dd = t * 8 + (lane >> 3);
            int npg = lane & 7;
            uint4 v = *(const uint4*)&ep[dd * 64 + ((npg ^ (dd & 7)) * 8)];
            *(uint4*)&v_out[((size_t)((b2 * 12 + h) * 64 + dd)) * 1024 + npos0 + npg * 8] = v;
        }
    }
}

// -------- attention: S^T form, 128 q/block, 2-deep V reg pipeline, swizzled LDS, l via MFMA --------
// Vs layout: row d (128B) as 16 x 8B chunks; global chunk c stored at position c ^ (d&15).
// V regs for tile i+1 are loaded at iter i-1 (full-iteration in flight); written to LDS at
// iter i with NO extra wait (top vmcnt(4) already drained them, issue order [V,V,K,K]).
__global__ __launch_bounds__(256) void attn128(
    u16* __restrict__ QO, const u16* __restrict__ Kg, const u16* __restrict__ Vtg)
{
    __shared__ __align__(16) u16 Ks[2][64 * 64];   // [kv][d], 16B groups XOR-swizzled
    __shared__ __align__(16) u16 Vs[2][64 * 64];   // [d][kv], 8B chunks swizzled c^(d&15)

    int tid = threadIdx.x;
    int lane = tid & 63, wave = tid >> 6;
    int quad = lane >> 4, l16 = lane & 15;
    int id = blockIdx.x;
    int xcd = id & 7, j = id >> 3;              // 12 heads per XCD
    int bh = xcd * 12 + (j >> 3);
    int q0 = (j & 7) * 128;
    const size_t head_base = (size_t)bh * 65536;

    size_t qoff[2];
    bf16x8 qf[2][2];
    #pragma unroll
    for (int qs = 0; qs < 2; qs++) {
        qoff[qs] = head_base + (size_t)(q0 + wave * 32 + qs * 16 + l16) * 64;
        qf[qs][0] = *(const bf16x8*)&QO[qoff[qs] + quad * 8];
        qf[qs][1] = *(const bf16x8*)&QO[qoff[qs] + 32 + quad * 8];
    }

    f32x4 Oacc[4][2];
    #pragma unroll
    for (int dt = 0; dt < 4; dt++)
        #pragma unroll
        for (int qs = 0; qs < 2; qs++) Oacc[dt][qs] = (f32x4){0.f, 0.f, 0.f, 0.f};
    f32x4 lacc[2];
    lacc[0] = (f32x4){0.f, 0.f, 0.f, 0.f};
    lacc[1] = (f32x4){0.f, 0.f, 0.f, 0.f};

    // ones A-fragment for l = sum_k P[k][q] via MFMA
    union { unsigned int w[4]; bf16x8 v; } ones;
    ones.w[0] = ones.w[1] = ones.w[2] = ones.w[3] = 0x3f803f80u;

    int srow = tid >> 3, sg = tid & 7;
    // K: cp16 with 16B-group source pre-swizzle
    int gsK = sg ^ (srow & 7);
    const u16* GK[2];
    GK[0] = Kg + head_base + (size_t)(srow) * 64 + gsK * 8;
    GK[1] = Kg + head_base + (size_t)(32 + srow) * 64 + gsK * 8;
    // V: natural global source (reg-staged), rows are d, 1024-wide kv
    const u16* GV[2];
    GV[0] = Vtg + head_base + (size_t)(srow) * 1024 + sg * 8;
    GV[1] = Vtg + head_base + (size_t)(32 + srow) * 1024 + sg * 8;
    // V LDS write offsets (u16 units): row r, chunks 2sg and 2sg+1 at pos c^(r&15)
    int vwA[2], vwB[2];
    #pragma unroll
    for (int it = 0; it < 2; it++) {
        int r = it * 32 + srow;
        vwA[it] = r * 64 + (((2 * sg)     ^ (r & 15)) * 4);
        vwB[it] = r * 64 + (((2 * sg + 1) ^ (r & 15)) * 4);
    }

    uint4 vA0, vA1, vB0, vB1;

    // prologue: V(0) -> LDS directly; V(1) -> regs (vA); K(0) cp16s last.
    {
        uint4 t0 = *(const uint4*)GV[0];
        uint4 t1 = *(const uint4*)GV[1];
        uint2 t;
        t.x = t0.x; t.y = t0.y; *(uint2*)&Vs[0][vwA[0]] = t;
        t.x = t0.z; t.y = t0.w; *(uint2*)&Vs[0][vwB[0]] = t;
        t.x = t1.x; t.y = t1.y; *(uint2*)&Vs[0][vwA[1]] = t;
        t.x = t1.z; t.y = t1.w; *(uint2*)&Vs[0][vwB[1]] = t;
    }
    vA0 = *(const uint4*)(GV[0] + 64);
    vA1 = *(const uint4*)(GV[1] + 64);
    cp16(GK[0], &Ks[0][(0 * 256 + tid) * 8]);
    cp16(GK[1], &Ks[0][(1 * 256 + tid) * 8]);
    asm volatile("s_waitcnt lgkmcnt(0)" ::: "memory");
    // outstanding entering loop: V(1)x2, K(0)x2  (matches steady state)

    // prefetch for iter I: V(I+2) regs into VN, K(I+1) cp16 into Ks[(I+1)&1]
    #define ATT_PF(I, PFV, PFK, VN0, VN1)                                        \
        if (PFV) {                                                               \
            VN0 = *(const uint4*)(GV[0] + ((I) + 2) * 64);                       \
            VN1 = *(const uint4*)(GV[1] + ((I) + 2) * 64);                       \
        }                                                                        \
        if (PFK) {                                                               \
            cp16(GK[0] + (size_t)((I) + 1) * 4096, &Ks[((I) + 1) & 1][(0 * 256 + tid) * 8]); \
            cp16(GK[1] + (size_t)((I) + 1) * 4096, &Ks[((I) + 1) & 1][(1 * 256 + tid) * 8]); \
        }

    // compute tile I from Ks[b], Vs[b]; write V(I+1) (regs VC, already drained) to Vs[b^1]
    #define ATT_COMP(I, WRV, VC0, VC1)                                           \
    {                                                                            \
        int b = (I) & 1;                                                         \
        __builtin_amdgcn_s_barrier();                                            \
        bf16x8 kf[4][2];                                                         \
        _Pragma("unroll")                                                        \
        for (int nt = 0; nt < 4; nt++) {                                         \
            int R = nt * 16 + l16;                                               \
            kf[nt][0] = *(const bf16x8*)&Ks[b][R * 64 + ((quad       ^ (R & 7)) * 8)]; \
            kf[nt][1] = *(const bf16x8*)&Ks[b][R * 64 + (((quad + 4) ^ (R & 7)) * 8)]; \
        }                                                                        \
        if (WRV) {                                                               \
            uint2 t;                                                             \
            t.x = VC0.x; t.y = VC0.y; *(uint2*)&Vs[b ^ 1][vwA[0]] = t;           \
            t.x = VC0.z; t.y = VC0.w; *(uint2*)&Vs[b ^ 1][vwB[0]] = t;           \
            t.x = VC1.x; t.y = VC1.y; *(uint2*)&Vs[b ^ 1][vwA[1]] = t;           \
            t.x = VC1.z; t.y = VC1.w; *(uint2*)&Vs[b ^ 1][vwB[1]] = t;           \
        }                                                                        \
        f32x4 s4[4][2];                                                          \
        _Pragma("unroll")                                                        \
        for (int nt = 0; nt < 4; nt++)                                           \
            _Pragma("unroll")                                                    \
            for (int qs = 0; qs < 2; qs++) {                                     \
                f32x4 s = (f32x4){0.f, 0.f, 0.f, 0.f};                           \
                s = __builtin_amdgcn_mfma_f32_16x16x32_bf16(kf[nt][0], qf[qs][0], s, 0, 0, 0); \
                s = __builtin_amdgcn_mfma_f32_16x16x32_bf16(kf[nt][1], qf[qs][1], s, 0, 0, 0); \
                s4[nt][qs] = s;                                                  \
            }                                                                    \
        float p[4][2][4];                                                        \
        _Pragma("unroll")                                                        \
        for (int nt = 0; nt < 4; nt++)                                           \
            _Pragma("unroll")                                                    \
            for (int qs = 0; qs < 2; qs++)                                       \
                _Pragma("unroll")                                                \
                for (int r = 0; r < 4; r++)                                      \
                    p[nt][qs][r] = __builtin_amdgcn_exp2f(s4[nt][qs][r]);        \
        __builtin_amdgcn_s_setprio(1);                                           \
        _Pragma("unroll")                                                        \
        for (int h = 0; h < 2; h++) {                                            \
            union { unsigned int w[4]; bf16x8 v; } pk[2];                        \
            _Pragma("unroll")                                                    \
            for (int qs = 0; qs < 2; qs++) {                                     \
                asm("v_cvt_pk_bf16_f32 %0, %1, %2" : "=v"(pk[qs].w[0]) : "v"(p[2*h][qs][0]),   "v"(p[2*h][qs][1])); \
                asm("v_cvt_pk_bf16_f32 %0, %1, %2" : "=v"(pk[qs].w[1]) : "v"(p[2*h][qs][2]),   "v"(p[2*h][qs][3])); \
                asm("v_cvt_pk_bf16_f32 %0, %1, %2" : "=v"(pk[qs].w[2]) : "v"(p[2*h+1][qs][0]), "v"(p[2*h+1][qs][1])); \
                asm("v_cvt_pk_bf16_f32 %0, %1, %2" : "=v"(pk[qs].w[3]) : "v"(p[2*h+1][qs][2]), "v"(p[2*h+1][qs][3])); \
                lacc[qs] = __builtin_amdgcn_mfma_f32_16x16x32_bf16(ones.v, pk[qs].v, lacc[qs], 0, 0, 0); \
            }                                                                    \
            int pbase = ((8 * h + quad) ^ l16) * 4;                              \
            _Pragma("unroll")                                                    \
            for (int dt = 0; dt < 4; dt++) {                                     \
                int drow = dt * 16 + l16;                                        \
                union { u16 s[8]; bf16x8 v; } vk;                                \
                *(uint2*)&vk.s[0] = *(const uint2*)&Vs[b][drow * 64 + pbase];    \
                *(uint2*)&vk.s[4] = *(const uint2*)&Vs[b][drow * 64 + (pbase ^ 16)]; \
                _Pragma("unroll")                                                \
                for (int qs = 0; qs < 2; qs++)                                   \
                    Oacc[dt][qs] = __builtin_amdgcn_mfma_f32_16x16x32_bf16(vk.v, pk[qs].v, Oacc[dt][qs], 0, 0, 0); \
            }                                                                    \
        }                                                                        \
        __builtin_amdgcn_s_setprio(0);                                           \
        asm volatile("s_waitcnt lgkmcnt(0)" ::: "memory");                       \
        __builtin_amdgcn_s_barrier();                                            \
    }

    // main: i = 0..13, unrolled x2 so V reg sets alternate with no copies
    for (int ii = 0; ii < 7; ii++) {
        int i0 = 2 * ii, i1 = i0 + 1;
        ATT_PF(i0, 1, 1, vB0, vB1)
        asm volatile("s_waitcnt vmcnt(4)" ::: "memory");   // drain V(i0+1)+K(i0)
        ATT_COMP(i0, 1, vA0, vA1)
        ATT_PF(i1, 1, 1, vA0, vA1)
        asm volatile("s_waitcnt vmcnt(4)" ::: "memory");
        ATT_COMP(i1, 1, vB0, vB1)
    }
    // i = 14: no V prefetch (tile 16 doesn't exist); K(15) only
    ATT_PF(14, 0, 1, vB0, vB1)
    asm volatile("s_waitcnt vmcnt(2)" ::: "memory");       // drain V(15)+K(14)
    ATT_COMP(14, 1, vA0, vA1)
    // i = 15: nothing in flight to keep
    asm volatile("s_waitcnt vmcnt(0)" ::: "memory");
    ATT_COMP(15, 0, vB0, vB1)

    #undef ATT_PF
    #undef ATT_COMP

    #pragma unroll
    for (int qs = 0; qs < 2; qs++) {
        float rl = __builtin_amdgcn_rcpf(lacc[qs][0]);   // l[q=l16], replicated in all regs
        #pragma unroll
        for (int dt = 0; dt < 4; dt++) {
            union { u16 s[4]; uint2 v; } ok;
            #pragma unroll
            for (int r = 0; r < 4; r++) ok.s[r] = f2bf(Oacc[dt][qs][r] * rl);
            *(uint2*)&QO[qoff[qs] + dt * 16 + quad * 4] = ok.v;
        }
    }
}

// -------- out-proj GEMM: BK=64, dbuf, counted-vmcnt pipeline, XCD-pinned --------
__global__ __launch_bounds__(256) void gemm_out(
    const u16* __restrict__ Qg, const u16* __restrict__ Bt,
    const float* __restrict__ bias, float* __restrict__ out)
{
    const int K = 768;
    __shared__ __align__(16) u16 As[2][128 * 64];
    __shared__ __align__(16) u16 Bs[2][128 * 64];

    int tid = threadIdx.x;
    int lane = tid & 63, wave = tid >> 6;
    int quad = lane >> 4, l16 = lane & 15;
    int wm = wave >> 1, wn = wave & 1;
    int id = blockIdx.x;
    int xcd = id & 7, j = id >> 3;
    int m0 = (((j & 7) << 3) + xcd) * 128;
    int n0 = (j >> 3) * 128;

    f32x4 acc[4][4];
    #pragma unroll
    for (int i = 0; i < 4; i++)
        #pragma unroll
        for (int jj = 0; jj < 4; jj++) acc[i][jj] = (f32x4){0.f, 0.f, 0.f, 0.f};

    int r0 = tid >> 3, cg = tid & 7;
    int g = cg ^ (r0 & 7);
    const u16* GA[4]; const u16* GB[4];
    #pragma unroll
    for (int it = 0; it < 4; it++) {
        int m = m0 + it * 32 + r0, b = m >> 10, npos = m & 1023;
        GA[it] = Qg + (((size_t)(b * 12) * 1024 + npos) << 6) + g * 8;  // + h*65536
        GB[it] = Bt + (size_t)(n0 + it * 32 + r0) * K + g * 8;          // + kt
    }

    #define STAGE_OUT(i2, b)                                              \
        _Pragma("unroll")                                                 \
        for (int it = 0; it < 4; it++) {                                  \
            cp16(GA[it] + (size_t)(i2) * 65536, &As[b][(it * 256 + tid) * 8]); \
            cp16(GB[it] + (i2) * 64,            &Bs[b][(it * 256 + tid) * 8]); \
        }

    STAGE_OUT(0, 0)
    for (int i = 0; i < 12; i++) {
        int b = i & 1;
        if (i + 1 < 12) {
            STAGE_OUT(i + 1, b ^ 1)
            asm volatile("s_waitcnt vmcnt(8)" ::: "memory");
        } else {
            asm volatile("s_waitcnt vmcnt(0)" ::: "memory");
        }
        __builtin_amdgcn_s_barrier();
        bf16x8 af[2][4], bfr[2][4];
        #pragma unroll
        for (int ko = 0; ko < 2; ko++)
            #pragma unroll
            for (int x = 0; x < 4; x++) {
                int Ra = wm * 64 + x * 16 + l16;
                af[ko][x]  = *(const bf16x8*)&As[b][Ra * 64 + (((ko * 4 + quad) ^ (Ra & 7)) * 8)];
                int Rb = wn * 64 + x * 16 + l16;
                bfr[ko][x] = *(const bf16x8*)&Bs[b][Rb * 64 + (((ko * 4 + quad) ^ (Rb & 7)) * 8)];
            }
        #pragma unroll
        for (int ko = 0; ko < 2; ko++)
            #pragma unroll
            for (int x = 0; x < 4; x++)
                #pragma unroll
                for (int y = 0; y < 4; y++)
                    acc[x][y] = __builtin_amdgcn_mfma_f32_16x16x32_bf16(af[ko][x], bfr[ko][y], acc[x][y], 0, 0, 0);
        __builtin_amdgcn_s_barrier();
    }
    #undef STAGE_OUT

    #pragma unroll
    for (int i = 0; i < 4; i++) {
        int mbase = m0 + wm * 64 + i * 16 + quad * 4;
        #pragma unroll
        for (int jj = 0; jj < 4; jj++) {
            int n = n0 + wn * 64 + jj * 16 + l16;
            float bv = bias[n];
            #pragma unroll
            for (int r = 0; r < 4; r++)
                out[(size_t)(mbase + r) * 768 + n] = acc[i][jj][r] + bv;
        }
    }
}

extern "C" void kernel_launch(void* const* d_in, const int* in_sizes, int n_in,
                              void* d_out, int out_size, void* d_ws, size_t ws_size,
                              hipStream_t stream) {
    const float* x     = (const float*)d_in[0];   // [8,1024,768] f32
    const float* w_qkv = (const float*)d_in[1];   // [768,2304] f32
    const float* w_out = (const float*)d_in[2];   // [768,768] f32
    const float* b_out = (const float*)d_in[3];   // [768] f32
    float* out = (float*)d_out;                   // [8,1024,768] f32

    char* ws = (char*)d_ws;
    u16* wtq  = (u16*)(ws);                   // [2304][768] bf16    3,538,944 B
    u16* wto  = (u16*)(ws + 3538944);         // [768][768]  bf16    1,179,648 B
    u16* Qbuf = (u16*)(ws + 4718592);         // [8,12,1024,64] bf16 12,582,912 B
    u16* xbf  = (u16*)(ws + 17301504);        // [8192][768] bf16    12,582,912 B  (29.9 MB)
    // K natural [b,h,n,64] and V TRANSPOSED [b,h,64,n] live in d_out (2x12.58 MB);
    // both fully consumed by attn128 before gemm_out overwrites d_out.
    u16* Kbuf = (u16*)d_out;
    u16* Vbuf = (u16*)d_out + 6291456;

    prep<<<dim3(5376), 256, 0, stream>>>(x, w_qkv, w_out, xbf, wtq, wto);
    gemm_qkv<<<dim3(1152), 256, 0, stream>>>(xbf, wtq, Qbuf, Kbuf, Vbuf);
    attn128<<<dim3(768), 256, 0, stream>>>(Qbuf, Kbuf, Vbuf);
    gemm_out<<<dim3(384), 256, 0, stream>>>(Qbuf, wto, b_out, out);
}

// Round 4
// 179.848 us; speedup vs baseline: 1.0699x; 1.0435x over previous
//
#include <hip/hip_runtime.h>

typedef unsigned short u16;
typedef __bf16 bf16x8 __attribute__((ext_vector_type(8)));
typedef float f32x4 __attribute__((ext_vector_type(4)));

__device__ inline u16 f2bf(float f) {
    union { float f; unsigned int u; } a; a.f = f;
    unsigned int u = a.u + 0x7fffu + ((a.u >> 16) & 1u);
    return (u16)(u >> 16);
}

// async global->LDS, 16B per lane. LDS side is wave-uniform base + lane*16.
__device__ __forceinline__ void cp16(const void* g, void* l) {
    __builtin_amdgcn_global_load_lds(
        (const __attribute__((address_space(1))) unsigned int*)g,
        (__attribute__((address_space(3))) unsigned int*)l, 16, 0, 0);
}

// -------- prep: fuse x-cast + both weight transposes (1 launch) --------
__global__ __launch_bounds__(256) void prep(
    const float* __restrict__ x, const float* __restrict__ wq,
    const float* __restrict__ wo, u16* __restrict__ xbf,
    u16* __restrict__ wtq, u16* __restrict__ wto)
{
    int bid = blockIdx.x;
    if (bid < 3072) {                      // cast x: f32 -> bf16, 8/thread
        size_t base = ((size_t)bid * 256 + threadIdx.x) * 8;
        float4 f0 = *(const float4*)&x[base];
        float4 f1 = *(const float4*)&x[base + 4];
        union { u16 s[8]; uint4 v; } t;
        t.s[0]=f2bf(f0.x); t.s[1]=f2bf(f0.y); t.s[2]=f2bf(f0.z); t.s[3]=f2bf(f0.w);
        t.s[4]=f2bf(f1.x); t.s[5]=f2bf(f1.y); t.s[6]=f2bf(f1.z); t.s[7]=f2bf(f1.w);
        *(uint4*)&xbf[base] = t.v;
        return;
    }
    __shared__ u16 tile[32][33];
    const float* in; u16* outp; int N, bx, by;
    if (bid < 3072 + 1728) { int t = bid - 3072; in = wq; outp = wtq; N = 2304; bx = t % 72; by = t / 72; }
    else                   { int t = bid - 4800; in = wo; outp = wto; N = 768;  bx = t % 24; by = t / 24; }
    int n0 = bx * 32, k0 = by * 32;
    int tx = threadIdx.x & 31, ty = threadIdx.x >> 5;
    #pragma unroll
    for (int r = ty; r < 32; r += 8)
        tile[r][tx] = f2bf(in[(size_t)(k0 + r) * N + n0 + tx]);
    __syncthreads();
    #pragma unroll
    for (int r = ty; r < 32; r += 8)
        outp[(size_t)(n0 + r) * 768 + k0 + tx] = tile[tx][r];
}

// -------- QKV GEMM: BK=64, dbuf, counted-vmcnt pipeline (T4), XCD-pinned --------
// A bf16 [8192][768], Bt bf16 [2304][768]
// Q (*0.125*log2e) -> [b,h,n,64]; K -> [b,h,n,64]; V -> TRANSPOSED [b,h,d,n]
__global__ __launch_bounds__(256) void gemm_qkv(
    const u16* __restrict__ A, const u16* __restrict__ Bt,
    u16* __restrict__ q_out, u16* __restrict__ k_out, u16* __restrict__ v_out)
{
    const int K = 768;
    __shared__ __align__(16) u16 As[2][128 * 64];   // slot s of row R holds k-group s^(R&7)
    __shared__ __align__(16) u16 Bs[2][128 * 64];

    int tid = threadIdx.x;
    int lane = tid & 63, wave = tid >> 6;
    int quad = lane >> 4, l16 = lane & 15;
    int wm = wave >> 1, wn = wave & 1;
    int id = blockIdx.x;
    int xcd = id & 7, j = id >> 3;
    int m0 = (((j & 7) << 3) + xcd) * 128;   // 64 m-tiles, XCD-pinned A slabs
    int n0 = (j >> 3) * 128;                 // 18 n-tiles

    f32x4 acc[4][4];
    #pragma unroll
    for (int i = 0; i < 4; i++)
        #pragma unroll
        for (int jj = 0; jj < 4; jj++) acc[i][jj] = (f32x4){0.f, 0.f, 0.f, 0.f};

    int r0 = tid >> 3, cg = tid & 7;
    int g = cg ^ (r0 & 7);                   // row&7 == r0&7 for all 4 its
    const u16* GA[4]; const u16* GB[4];
    #pragma unroll
    for (int it = 0; it < 4; it++) {
        GA[it] = A  + (size_t)(m0 + it * 32 + r0) * K + g * 8;
        GB[it] = Bt + (size_t)(n0 + it * 32 + r0) * K + g * 8;
    }

    #define STAGE_QKV(kt, b)                                          \
        _Pragma("unroll")                                             \
        for (int it = 0; it < 4; it++) {                              \
            cp16(GA[it] + (kt), &As[b][(it * 256 + tid) * 8]);        \
            cp16(GB[it] + (kt), &Bs[b][(it * 256 + tid) * 8]);        \
        }

    STAGE_QKV(0, 0)
    for (int i = 0; i < 12; i++) {
        int b = i & 1;
        // T4: issue next tile's loads FIRST, then wait only for tile i's 8 loads.
        if (i + 1 < 12) {
            STAGE_QKV((i + 1) * 64, b ^ 1)
            asm volatile("s_waitcnt vmcnt(8)" ::: "memory");
        } else {
            asm volatile("s_waitcnt vmcnt(0)" ::: "memory");
        }
        __builtin_amdgcn_s_barrier();        // all waves: tile i resident in buf b
        bf16x8 af[2][4], bfr[2][4];
        #pragma unroll
        for (int ko = 0; ko < 2; ko++)
            #pragma unroll
            for (int x = 0; x < 4; x++) {
                int Ra = wm * 64 + x * 16 + l16;
                af[ko][x]  = *(const bf16x8*)&As[b][Ra * 64 + (((ko * 4 + quad) ^ (Ra & 7)) * 8)];
                int Rb = wn * 64 + x * 16 + l16;
                bfr[ko][x] = *(const bf16x8*)&Bs[b][Rb * 64 + (((ko * 4 + quad) ^ (Rb & 7)) * 8)];
            }
        #pragma unroll
        for (int ko = 0; ko < 2; ko++)
            #pragma unroll
            for (int x = 0; x < 4; x++)
                #pragma unroll
                for (int y = 0; y < 4; y++)
                    acc[x][y] = __builtin_amdgcn_mfma_f32_16x16x32_bf16(af[ko][x], bfr[ko][y], acc[x][y], 0, 0, 0);
        __builtin_amdgcn_s_barrier();        // WAR: buf b fully read before iter i+1 overwrites it
    }
    #undef STAGE_QKV

    // ---- epilogue: wave tile = 64m x 64n, one (part,h); per-wave LDS region in buf0 ----
    int M0 = m0 + wm * 64, N0 = n0 + wn * 64;
    int part = N0 >= 1536 ? 2 : (N0 >= 768 ? 1 : 0);
    int h = (N0 - part * 768) >> 6;
    int b2 = M0 >> 10, npos0 = M0 & 1023;
    u16* ep = (wave < 2 ? As[0] : Bs[0]) + (wave & 1) * 4096;   // 8 KB per wave (buf0: free)

    if (part != 2) {
        float scale = (part == 0) ? 0.18033688011112042f : 1.0f;   // /8 * log2e for Q
        u16* gbase = (part == 0 ? q_out : k_out) + (((size_t)(b2 * 12 + h) * 1024 + npos0) << 6);
        #pragma unroll
        for (int i = 0; i < 4; i++)
            #pragma unroll
            for (int jj = 0; jj < 4; jj++) {
                int dd = jj * 16 + l16;
                #pragma unroll
                for (int r = 0; r < 4; r++) {
                    int np = i * 16 + quad * 4 + r;
                    ep[np * 64 + (((dd >> 3) ^ (np & 7)) * 8) + (dd & 7)] =
                        f2bf(acc[i][jj][r] * scale);
                }
            }
        #pragma unroll
        for (int t = 0; t < 8; t++) {        // per-wave region: ds order suffices, no barrier
            int idx = t * 512 + lane * 8;
            int np = idx >> 6;
            int slot = ((lane & 7) ^ (np & 7));
            uint4 v = *(const uint4*)&ep[np * 64 + slot * 8];
            *(uint4*)&gbase[idx] = v;
        }
    } else {
        #pragma unroll
        for (int i = 0; i < 4; i++)
            #pragma unroll
            for (int jj = 0; jj < 4; jj++) {
                int dd = jj * 16 + l16;
                int npg = i * 2 + (quad >> 1);
                int sub = (quad & 1) * 4;
                union { u16 s[4]; uint2 v; } pk;
                #pragma unroll
                for (int r = 0; r < 4; r++) pk.s[r] = f2bf(acc[i][jj][r]);
                *(uint2*)&ep[dd * 64 + ((npg ^ (dd & 7)) * 8) + sub] = pk.v;
            }
        #pragma unroll
        for (int t = 0; t < 8; t++) {
            int dd = t * 8 + (lane >> 3);
            int npg = lane & 7;
            uint4 v = *(const uint4*)&ep[dd * 64 + ((npg ^ (dd & 7)) * 8)];
            *(uint4*)&v_out[((size_t)((b2 * 12 + h) * 64 + dd)) * 1024 + npos0 + npg * 8] = v;
        }
    }
}

// -------- attention: 8 waves (512 thr), 16 q/wave, 1 barrier/iter, issue-after-barrier --------
// Latency-bound fix: 6 waves/SIMD resident (launch_bounds(512,6)), halved per-wave chain.
// Vs layout: row d as 16 x 8B chunks, chunk c at position c ^ (d&15) (conflict-free PV reads).
// Prefetch (K cp16 + V global->reg) issued right AFTER the barrier: all buf b^1 readers
// completed before the barrier, so no WAR barrier needed; drained by vmcnt(0) next iter.
__global__ __launch_bounds__(512, 6) void attn128(
    u16* __restrict__ QO, const u16* __restrict__ Kg, const u16* __restrict__ Vtg)
{
    __shared__ __align__(16) u16 Ks[2][64 * 64];   // [kv][d], 16B groups at pos g^(row&7)
    __shared__ __align__(16) u16 Vs[2][64 * 64];   // [d][kv], 8B chunks at pos c^(d&15)

    int tid = threadIdx.x;
    int lane = tid & 63, wave = tid >> 6;          // 8 waves
    int quad = lane >> 4, l16 = lane & 15;
    int id = blockIdx.x;
    int xcd = id & 7, j = id >> 3;                 // 12 heads per XCD
    int bh = xcd * 12 + (j >> 3);
    int q0 = (j & 7) * 128;
    const size_t head_base = (size_t)bh * 65536;

    size_t qoff = head_base + (size_t)(q0 + wave * 16 + l16) * 64;
    bf16x8 qf0 = *(const bf16x8*)&QO[qoff + quad * 8];
    bf16x8 qf1 = *(const bf16x8*)&QO[qoff + 32 + quad * 8];

    f32x4 Oacc[4];
    #pragma unroll
    for (int dt = 0; dt < 4; dt++) Oacc[dt] = (f32x4){0.f, 0.f, 0.f, 0.f};
    f32x4 lacc = (f32x4){0.f, 0.f, 0.f, 0.f};

    // ones A-fragment for l = sum_k P[k][q] via MFMA
    union { unsigned int w[4]; bf16x8 v; } ones;
    ones.w[0] = ones.w[1] = ones.w[2] = ones.w[3] = 0x3f803f80u;

    int srow = tid >> 3, sg = tid & 7;             // 512 thr cover 64 rows x 128B
    int gsK = sg ^ (srow & 7);
    const u16* GK = Kg + head_base + (size_t)srow * 64 + gsK * 8;
    const u16* GV = Vtg + head_base + (size_t)srow * 1024 + sg * 8;
    const int vwA = srow * 64 + (((2 * sg)     ^ (srow & 15)) * 4);
    const int vwB = srow * 64 + (((2 * sg + 1) ^ (srow & 15)) * 4);

    uint4 vA, vB;
    // prologue: V(0) -> LDS direct; V(1) -> regs; K(0) cp16
    {
        uint4 t0 = *(const uint4*)GV;
        uint2 t;
        t.x = t0.x; t.y = t0.y; *(uint2*)&Vs[0][vwA] = t;
        t.x = t0.z; t.y = t0.w; *(uint2*)&Vs[0][vwB] = t;
    }
    vA = *(const uint4*)(GV + 64);
    cp16(GK, &Ks[0][tid * 8]);

    // one barrier per iter; prefetch issued after it, drained at next iter's vmcnt(0)
    #define ATT_STEP(I, DO_K, DO_LD, VLD, DO_WR, VWR)                            \
    {                                                                            \
        const int b = (I) & 1;                                                   \
        asm volatile("s_waitcnt vmcnt(0)" ::: "memory");                         \
        asm volatile("s_waitcnt lgkmcnt(0)" ::: "memory");                       \
        __builtin_amdgcn_s_barrier();                                            \
        if (DO_K) cp16(GK + (size_t)((I) + 1) * 4096, &Ks[b ^ 1][tid * 8]);      \
        if (DO_LD) VLD = *(const uint4*)(GV + ((I) + 2) * 64);                   \
        if (DO_WR) {                                                             \
            uint2 t;                                                             \
            t.x = VWR.x; t.y = VWR.y; *(uint2*)&Vs[b ^ 1][vwA] = t;              \
            t.x = VWR.z; t.y = VWR.w; *(uint2*)&Vs[b ^ 1][vwB] = t;              \
        }                                                                        \
        f32x4 s4[4];                                                             \
        _Pragma("unroll")                                                        \
        for (int nt = 0; nt < 4; nt++) {                                         \
            int R = nt * 16 + l16;                                               \
            bf16x8 kf0 = *(const bf16x8*)&Ks[b][R * 64 + ((quad       ^ (R & 7)) * 8)]; \
            bf16x8 kf1 = *(const bf16x8*)&Ks[b][R * 64 + (((quad + 4) ^ (R & 7)) * 8)]; \
            f32x4 s = (f32x4){0.f, 0.f, 0.f, 0.f};                               \
            s = __builtin_amdgcn_mfma_f32_16x16x32_bf16(kf0, qf0, s, 0, 0, 0);   \
            s = __builtin_amdgcn_mfma_f32_16x16x32_bf16(kf1, qf1, s, 0, 0, 0);   \
            s4[nt] = s;                                                          \
        }                                                                        \
        float p[4][4];                                                           \
        _Pragma("unroll")                                                        \
        for (int nt = 0; nt < 4; nt++)                                           \
            _Pragma("unroll")                                                    \
            for (int r = 0; r < 4; r++)                                          \
                p[nt][r] = __builtin_amdgcn_exp2f(s4[nt][r]);                    \
        __builtin_amdgcn_s_setprio(1);                                           \
        _Pragma("unroll")                                                        \
        for (int h = 0; h < 2; h++) {                                            \
            union { unsigned int w[4]; bf16x8 v; } pk;                           \
            asm("v_cvt_pk_bf16_f32 %0, %1, %2" : "=v"(pk.w[0]) : "v"(p[2*h][0]),   "v"(p[2*h][1]));   \
            asm("v_cvt_pk_bf16_f32 %0, %1, %2" : "=v"(pk.w[1]) : "v"(p[2*h][2]),   "v"(p[2*h][3]));   \
            asm("v_cvt_pk_bf16_f32 %0, %1, %2" : "=v"(pk.w[2]) : "v"(p[2*h+1][0]), "v"(p[2*h+1][1])); \
            asm("v_cvt_pk_bf16_f32 %0, %1, %2" : "=v"(pk.w[3]) : "v"(p[2*h+1][2]), "v"(p[2*h+1][3])); \
            lacc = __builtin_amdgcn_mfma_f32_16x16x32_bf16(ones.v, pk.v, lacc, 0, 0, 0); \
            int pbase = ((8 * h + quad) ^ l16) * 4;                              \
            _Pragma("unroll")                                                    \
            for (int dt = 0; dt < 4; dt++) {                                     \
                int drow = dt * 16 + l16;                                        \
                union { u16 s[8]; bf16x8 v; } vk;                                \
                *(uint2*)&vk.s[0] = *(const uint2*)&Vs[b][drow * 64 + pbase];    \
                *(uint2*)&vk.s[4] = *(const uint2*)&Vs[b][drow * 64 + (pbase ^ 16)]; \
                Oacc[dt] = __builtin_amdgcn_mfma_f32_16x16x32_bf16(vk.v, pk.v, Oacc[dt], 0, 0, 0); \
            }                                                                    \
        }                                                                        \
        __builtin_amdgcn_s_setprio(0);                                           \
    }

    // main: unrolled x2 so V reg sets alternate with no copies
    for (int ii = 0; ii < 7; ii++) {
        ATT_STEP(2 * ii,     1, 1, vB, 1, vA)      // write V(i+1)=vA, load V(i+2)->vB
        ATT_STEP(2 * ii + 1, 1, 1, vA, 1, vB)
    }
    ATT_STEP(14, 1, 0, vB, 1, vA)                  // K(15) only; write V(15)=vA
    ATT_STEP(15, 0, 0, vA, 0, vB)                  // drain & compute last tile
    #undef ATT_STEP

    {
        float rl = __builtin_amdgcn_rcpf(lacc[0]);   // l for col q=l16 (rows identical)
        #pragma unroll
        for (int dt = 0; dt < 4; dt++) {
            union { u16 s[4]; uint2 v; } ok;
            #pragma unroll
            for (int r = 0; r < 4; r++) ok.s[r] = f2bf(Oacc[dt][r] * rl);
            *(uint2*)&QO[qoff + dt * 16 + quad * 4] = ok.v;
        }
    }
}

// -------- out-proj GEMM: BK=64, dbuf, counted-vmcnt pipeline, XCD-pinned --------
__global__ __launch_bounds__(256) void gemm_out(
    const u16* __restrict__ Qg, const u16* __restrict__ Bt,
    const float* __restrict__ bias, float* __restrict__ out)
{
    const int K = 768;
    __shared__ __align__(16) u16 As[2][128 * 64];
    __shared__ __align__(16) u16 Bs[2][128 * 64];

    int tid = threadIdx.x;
    int lane = tid & 63, wave = tid >> 6;
    int quad = lane >> 4, l16 = lane & 15;
    int wm = wave >> 1, wn = wave & 1;
    int id = blockIdx.x;
    int xcd = id & 7, j = id >> 3;
    int m0 = (((j & 7) << 3) + xcd) * 128;
    int n0 = (j >> 3) * 128;

    f32x4 acc[4][4];
    #pragma unroll
    for (int i = 0; i < 4; i++)
        #pragma unroll
        for (int jj = 0; jj < 4; jj++) acc[i][jj] = (f32x4){0.f, 0.f, 0.f, 0.f};

    int r0 = tid >> 3, cg = tid & 7;
    int g = cg ^ (r0 & 7);
    const u16* GA[4]; const u16* GB[4];
    #pragma unroll
    for (int it = 0; it < 4; it++) {
        int m = m0 + it * 32 + r0, b = m >> 10, npos = m & 1023;
        GA[it] = Qg + (((size_t)(b * 12) * 1024 + npos) << 6) + g * 8;  // + h*65536
        GB[it] = Bt + (size_t)(n0 + it * 32 + r0) * K + g * 8;          // + kt
    }

    #define STAGE_OUT(i2, b)                                              \
        _Pragma("unroll")                                                 \
        for (int it = 0; it < 4; it++) {                                  \
            cp16(GA[it] + (size_t)(i2) * 65536, &As[b][(it * 256 + tid) * 8]); \
            cp16(GB[it] + (i2) * 64,            &Bs[b][(it * 256 + tid) * 8]); \
        }

    STAGE_OUT(0, 0)
    for (int i = 0; i < 12; i++) {
        int b = i & 1;
        if (i + 1 < 12) {
            STAGE_OUT(i + 1, b ^ 1)
            asm volatile("s_waitcnt vmcnt(8)" ::: "memory");
        } else {
            asm volatile("s_waitcnt vmcnt(0)" ::: "memory");
        }
        __builtin_amdgcn_s_barrier();
        bf16x8 af[2][4], bfr[2][4];
        #pragma unroll
        for (int ko = 0; ko < 2; ko++)
            #pragma unroll
            for (int x = 0; x < 4; x++) {
                int Ra = wm * 64 + x * 16 + l16;
                af[ko][x]  = *(const bf16x8*)&As[b][Ra * 64 + (((ko * 4 + quad) ^ (Ra & 7)) * 8)];
                int Rb = wn * 64 + x * 16 + l16;
                bfr[ko][x] = *(const bf16x8*)&Bs[b][Rb * 64 + (((ko * 4 + quad) ^ (Rb & 7)) * 8)];
            }
        #pragma unroll
        for (int ko = 0; ko < 2; ko++)
            #pragma unroll
            for (int x = 0; x < 4; x++)
                #pragma unroll
                for (int y = 0; y < 4; y++)
                    acc[x][y] = __builtin_amdgcn_mfma_f32_16x16x32_bf16(af[ko][x], bfr[ko][y], acc[x][y], 0, 0, 0);
        __builtin_amdgcn_s_barrier();
    }
    #undef STAGE_OUT

    #pragma unroll
    for (int i = 0; i < 4; i++) {
        int mbase = m0 + wm * 64 + i * 16 + quad * 4;
        #pragma unroll
        for (int jj = 0; jj < 4; jj++) {
            int n = n0 + wn * 64 + jj * 16 + l16;
            float bv = bias[n];
            #pragma unroll
            for (int r = 0; r < 4; r++)
                out[(size_t)(mbase + r) * 768 + n] = acc[i][jj][r] + bv;
        }
    }
}

extern "C" void kernel_launch(void* const* d_in, const int* in_sizes, int n_in,
                              void* d_out, int out_size, void* d_ws, size_t ws_size,
                              hipStream_t stream) {
    const float* x     = (const float*)d_in[0];   // [8,1024,768] f32
    const float* w_qkv = (const float*)d_in[1];   // [768,2304] f32
    const float* w_out = (const float*)d_in[2];   // [768,768] f32
    const float* b_out = (const float*)d_in[3];   // [768] f32
    float* out = (float*)d_out;                   // [8,1024,768] f32

    char* ws = (char*)d_ws;
    u16* wtq  = (u16*)(ws);                   // [2304][768] bf16    3,538,944 B
    u16* wto  = (u16*)(ws + 3538944);         // [768][768]  bf16    1,179,648 B
    u16* Qbuf = (u16*)(ws + 4718592);         // [8,12,1024,64] bf16 12,582,912 B
    u16* xbf  = (u16*)(ws + 17301504);        // [8192][768] bf16    12,582,912 B  (29.9 MB)
    // K natural [b,h,n,64] and V TRANSPOSED [b,h,64,n] live in d_out (2x12.58 MB);
    // both fully consumed by attn128 before gemm_out overwrites d_out.
    u16* Kbuf = (u16*)d_out;
    u16* Vbuf = (u16*)d_out + 6291456;

    prep<<<dim3(5376), 256, 0, stream>>>(x, w_qkv, w_out, xbf, wtq, wto);
    gemm_qkv<<<dim3(1152), 256, 0, stream>>>(xbf, wtq, Qbuf, Kbuf, Vbuf);
    attn128<<<dim3(768), 512, 0, stream>>>(Qbuf, Kbuf, Vbuf);
    gemm_out<<<dim3(384), 256, 0, stream>>>(Qbuf, wto, b_out, out);
}

// Round 6
// 172.842 us; speedup vs baseline: 1.1133x; 1.0405x over previous
//
#include <hip/hip_runtime.h>

typedef unsigned short u16;
typedef __bf16 bf16x8 __attribute__((ext_vector_type(8)));
typedef float f32x4 __attribute__((ext_vector_type(4)));

__device__ inline u16 f2bf(float f) {
    union { float f; unsigned int u; } a; a.f = f;
    unsigned int u = a.u + 0x7fffu + ((a.u >> 16) & 1u);
    return (u16)(u >> 16);
}

// async global->LDS, 16B per lane. LDS side is wave-uniform base + lane*16.
__device__ __forceinline__ void cp16(const void* g, void* l) {
    __builtin_amdgcn_global_load_lds(
        (const __attribute__((address_space(1))) unsigned int*)g,
        (__attribute__((address_space(3))) unsigned int*)l, 16, 0, 0);
}

// -------- prep: fuse x-cast + both weight transposes (1 launch) --------
__global__ __launch_bounds__(256) void prep(
    const float* __restrict__ x, const float* __restrict__ wq,
    const float* __restrict__ wo, u16* __restrict__ xbf,
    u16* __restrict__ wtq, u16* __restrict__ wto)
{
    int bid = blockIdx.x;
    if (bid < 3072) {                      // cast x: f32 -> bf16, 8/thread
        size_t base = ((size_t)bid * 256 + threadIdx.x) * 8;
        float4 f0 = *(const float4*)&x[base];
        float4 f1 = *(const float4*)&x[base + 4];
        union { u16 s[8]; uint4 v; } t;
        t.s[0]=f2bf(f0.x); t.s[1]=f2bf(f0.y); t.s[2]=f2bf(f0.z); t.s[3]=f2bf(f0.w);
        t.s[4]=f2bf(f1.x); t.s[5]=f2bf(f1.y); t.s[6]=f2bf(f1.z); t.s[7]=f2bf(f1.w);
        *(uint4*)&xbf[base] = t.v;
        return;
    }
    __shared__ u16 tile[32][33];
    const float* in; u16* outp; int N, bx, by;
    if (bid < 3072 + 1728) { int t = bid - 3072; in = wq; outp = wtq; N = 2304; bx = t % 72; by = t / 72; }
    else                   { int t = bid - 4800; in = wo; outp = wto; N = 768;  bx = t % 24; by = t / 24; }
    int n0 = bx * 32, k0 = by * 32;
    int tx = threadIdx.x & 31, ty = threadIdx.x >> 5;
    #pragma unroll
    for (int r = ty; r < 32; r += 8)
        tile[r][tx] = f2bf(in[(size_t)(k0 + r) * N + n0 + tx]);
    __syncthreads();
    #pragma unroll
    for (int r = ty; r < 32; r += 8)
        outp[(size_t)(n0 + r) * 768 + k0 + tx] = tile[tx][r];
}

// -------- QKV GEMM: BK=64, dbuf, counted-vmcnt pipeline (T4), XCD-pinned --------
// A bf16 [8192][768], Bt bf16 [2304][768]
// Q (*0.125*log2e) -> [b,h,n,64]; K -> [b,h,n,64]; V -> TRANSPOSED [b,h,d,n]
__global__ __launch_bounds__(256) void gemm_qkv(
    const u16* __restrict__ A, const u16* __restrict__ Bt,
    u16* __restrict__ q_out, u16* __restrict__ k_out, u16* __restrict__ v_out)
{
    const int K = 768;
    __shared__ __align__(16) u16 As[2][128 * 64];   // slot s of row R holds k-group s^(R&7)
    __shared__ __align__(16) u16 Bs[2][128 * 64];

    int tid = threadIdx.x;
    int lane = tid & 63, wave = tid >> 6;
    int quad = lane >> 4, l16 = lane & 15;
    int wm = wave >> 1, wn = wave & 1;
    int id = blockIdx.x;
    int xcd = id & 7, j = id >> 3;
    int m0 = (((j & 7) << 3) + xcd) * 128;   // 64 m-tiles, XCD-pinned A slabs
    int n0 = (j >> 3) * 128;                 // 18 n-tiles

    f32x4 acc[4][4];
    #pragma unroll
    for (int i = 0; i < 4; i++)
        #pragma unroll
        for (int jj = 0; jj < 4; jj++) acc[i][jj] = (f32x4){0.f, 0.f, 0.f, 0.f};

    int r0 = tid >> 3, cg = tid & 7;
    int g = cg ^ (r0 & 7);                   // row&7 == r0&7 for all 4 its
    const u16* GA[4]; const u16* GB[4];
    #pragma unroll
    for (int it = 0; it < 4; it++) {
        GA[it] = A  + (size_t)(m0 + it * 32 + r0) * K + g * 8;
        GB[it] = Bt + (size_t)(n0 + it * 32 + r0) * K + g * 8;
    }

    #define STAGE_QKV(kt, b)                                          \
        _Pragma("unroll")                                             \
        for (int it = 0; it < 4; it++) {                              \
            cp16(GA[it] + (kt), &As[b][(it * 256 + tid) * 8]);        \
            cp16(GB[it] + (kt), &Bs[b][(it * 256 + tid) * 8]);        \
        }

    STAGE_QKV(0, 0)
    for (int i = 0; i < 12; i++) {
        int b = i & 1;
        // T4: issue next tile's loads FIRST, then wait only for tile i's 8 loads.
        if (i + 1 < 12) {
            STAGE_QKV((i + 1) * 64, b ^ 1)
            asm volatile("s_waitcnt vmcnt(8)" ::: "memory");
        } else {
            asm volatile("s_waitcnt vmcnt(0)" ::: "memory");
        }
        __builtin_amdgcn_s_barrier();        // all waves: tile i resident in buf b
        bf16x8 af[2][4], bfr[2][4];
        #pragma unroll
        for (int ko = 0; ko < 2; ko++)
            #pragma unroll
            for (int x = 0; x < 4; x++) {
                int Ra = wm * 64 + x * 16 + l16;
                af[ko][x]  = *(const bf16x8*)&As[b][Ra * 64 + (((ko * 4 + quad) ^ (Ra & 7)) * 8)];
                int Rb = wn * 64 + x * 16 + l16;
                bfr[ko][x] = *(const bf16x8*)&Bs[b][Rb * 64 + (((ko * 4 + quad) ^ (Rb & 7)) * 8)];
            }
        #pragma unroll
        for (int ko = 0; ko < 2; ko++)
            #pragma unroll
            for (int x = 0; x < 4; x++)
                #pragma unroll
                for (int y = 0; y < 4; y++)
                    acc[x][y] = __builtin_amdgcn_mfma_f32_16x16x32_bf16(af[ko][x], bfr[ko][y], acc[x][y], 0, 0, 0);
        __builtin_amdgcn_s_barrier();        // WAR: buf b fully read before iter i+1 overwrites it
    }
    #undef STAGE_QKV

    // ---- epilogue: wave tile = 64m x 64n, one (part,h); per-wave LDS region in buf0 ----
    int M0 = m0 + wm * 64, N0 = n0 + wn * 64;
    int part = N0 >= 1536 ? 2 : (N0 >= 768 ? 1 : 0);
    int h = (N0 - part * 768) >> 6;
    int b2 = M0 >> 10, npos0 = M0 & 1023;
    u16* ep = (wave < 2 ? As[0] : Bs[0]) + (wave & 1) * 4096;   // 8 KB per wave (buf0: free)

    if (part != 2) {
        float scale = (part == 0) ? 0.18033688011112042f : 1.0f;   // /8 * log2e for Q
        u16* gbase = (part == 0 ? q_out : k_out) + (((size_t)(b2 * 12 + h) * 1024 + npos0) << 6);
        #pragma unroll
        for (int i = 0; i < 4; i++)
            #pragma unroll
            for (int jj = 0; jj < 4; jj++) {
                int dd = jj * 16 + l16;
                #pragma unroll
                for (int r = 0; r < 4; r++) {
                    int np = i * 16 + quad * 4 + r;
                    ep[np * 64 + (((dd >> 3) ^ (np & 7)) * 8) + (dd & 7)] =
                        f2bf(acc[i][jj][r] * scale);
                }
            }
        #pragma unroll
        for (int t = 0; t < 8; t++) {        // per-wave region: ds order suffices, no barrier
            int idx = t * 512 + lane * 8;
            int np = idx >> 6;
            int slot = ((lane & 7) ^ (np & 7));
            uint4 v = *(const uint4*)&ep[np * 64 + slot * 8];
            *(uint4*)&gbase[idx] = v;
        }
    } else {
        #pragma unroll
        for (int i = 0; i < 4; i++)
            #pragma unroll
            for (int jj = 0; jj < 4; jj++) {
                int dd = jj * 16 + l16;
                int npg = i * 2 + (quad >> 1);
                int sub = (quad & 1) * 4;
                union { u16 s[4]; uint2 v; } pk;
                #pragma unroll
                for (int r = 0; r < 4; r++) pk.s[r] = f2bf(acc[i][jj][r]);
                *(uint2*)&ep[dd * 64 + ((npg ^ (dd & 7)) * 8) + sub] = pk.v;
            }
        #pragma unroll
        for (int t = 0; t < 8; t++) {
            int dd = t * 8 + (lane >> 3);
            int npg = lane & 7;
            uint4 v = *(const uint4*)&ep[dd * 64 + ((npg ^ (dd & 7)) * 8)];
            *(uint4*)&v_out[((size_t)((b2 * 12 + h) * 64 + dd)) * 1024 + npos0 + npg * 8] = v;
        }
    }
}

// -------- attention: 8 waves (512 thr), 16 q/wave, 1 barrier/iter (R4-exact passing text) --------
__global__ __launch_bounds__(512, 6) void attn128(
    u16* __restrict__ QO, const u16* __restrict__ Kg, const u16* __restrict__ Vtg)
{
    __shared__ __align__(16) u16 Ks[2][64 * 64];   // [kv][d], 16B groups at pos g^(row&7)
    __shared__ __align__(16) u16 Vs[2][64 * 64];   // [d][kv], 8B chunks at pos c^(d&15)

    int tid = threadIdx.x;
    int lane = tid & 63, wave = tid >> 6;          // 8 waves
    int quad = lane >> 4, l16 = lane & 15;
    int id = blockIdx.x;
    int xcd = id & 7, j = id >> 3;                 // 12 heads per XCD
    int bh = xcd * 12 + (j >> 3);
    int q0 = (j & 7) * 128;
    const size_t head_base = (size_t)bh * 65536;

    size_t qoff = head_base + (size_t)(q0 + wave * 16 + l16) * 64;
    bf16x8 qf0 = *(const bf16x8*)&QO[qoff + quad * 8];
    bf16x8 qf1 = *(const bf16x8*)&QO[qoff + 32 + quad * 8];

    f32x4 Oacc[4];
    #pragma unroll
    for (int dt = 0; dt < 4; dt++) Oacc[dt] = (f32x4){0.f, 0.f, 0.f, 0.f};
    f32x4 lacc = (f32x4){0.f, 0.f, 0.f, 0.f};

    // ones A-fragment for l = sum_k P[k][q] via MFMA
    union { unsigned int w[4]; bf16x8 v; } ones;
    ones.w[0] = ones.w[1] = ones.w[2] = ones.w[3] = 0x3f803f80u;

    int srow = tid >> 3, sg = tid & 7;             // 512 thr cover 64 rows x 128B
    int gsK = sg ^ (srow & 7);
    const u16* GK = Kg + head_base + (size_t)srow * 64 + gsK * 8;
    const u16* GV = Vtg + head_base + (size_t)srow * 1024 + sg * 8;
    const int vwA = srow * 64 + (((2 * sg)     ^ (srow & 15)) * 4);
    const int vwB = srow * 64 + (((2 * sg + 1) ^ (srow & 15)) * 4);

    uint4 vA, vB;
    // prologue: V(0) -> LDS direct; V(1) -> regs; K(0) cp16
    {
        uint4 t0 = *(const uint4*)GV;
        uint2 t;
        t.x = t0.x; t.y = t0.y; *(uint2*)&Vs[0][vwA] = t;
        t.x = t0.z; t.y = t0.w; *(uint2*)&Vs[0][vwB] = t;
    }
    vA = *(const uint4*)(GV + 64);
    cp16(GK, &Ks[0][tid * 8]);

    // one barrier per iter; prefetch issued after it, drained at next iter's vmcnt(0)
    #define ATT_STEP(I, DO_K, DO_LD, VLD, DO_WR, VWR)                            \
    {                                                                            \
        const int b = (I) & 1;                                                   \
        asm volatile("s_waitcnt vmcnt(0)" ::: "memory");                         \
        asm volatile("s_waitcnt lgkmcnt(0)" ::: "memory");                       \
        __builtin_amdgcn_s_barrier();                                            \
        if (DO_K) cp16(GK + (size_t)((I) + 1) * 4096, &Ks[b ^ 1][tid * 8]);      \
        if (DO_LD) VLD = *(const uint4*)(GV + ((I) + 2) * 64);                   \
        if (DO_WR) {                                                             \
            uint2 t;                                                             \
            t.x = VWR.x; t.y = VWR.y; *(uint2*)&Vs[b ^ 1][vwA] = t;              \
            t.x = VWR.z; t.y = VWR.w; *(uint2*)&Vs[b ^ 1][vwB] = t;              \
        }                                                                        \
        f32x4 s4[4];                                                             \
        _Pragma("unroll")                                                        \
        for (int nt = 0; nt < 4; nt++) {                                         \
            int R = nt * 16 + l16;                                               \
            bf16x8 kf0 = *(const bf16x8*)&Ks[b][R * 64 + ((quad       ^ (R & 7)) * 8)]; \
            bf16x8 kf1 = *(const bf16x8*)&Ks[b][R * 64 + (((quad + 4) ^ (R & 7)) * 8)]; \
            f32x4 s = (f32x4){0.f, 0.f, 0.f, 0.f};                               \
            s = __builtin_amdgcn_mfma_f32_16x16x32_bf16(kf0, qf0, s, 0, 0, 0);   \
            s = __builtin_amdgcn_mfma_f32_16x16x32_bf16(kf1, qf1, s, 0, 0, 0);   \
            s4[nt] = s;                                                          \
        }                                                                        \
        float p[4][4];                                                           \
        _Pragma("unroll")                                                        \
        for (int nt = 0; nt < 4; nt++)                                           \
            _Pragma("unroll")                                                    \
            for (int r = 0; r < 4; r++)                                          \
                p[nt][r] = __builtin_amdgcn_exp2f(s4[nt][r]);                    \
        __builtin_amdgcn_s_setprio(1);                                           \
        _Pragma("unroll")                                                        \
        for (int h = 0; h < 2; h++) {                                            \
            union { unsigned int w[4]; bf16x8 v; } pk;                           \
            asm("v_cvt_pk_bf16_f32 %0, %1, %2" : "=v"(pk.w[0]) : "v"(p[2*h][0]),   "v"(p[2*h][1]));   \
            asm("v_cvt_pk_bf16_f32 %0, %1, %2" : "=v"(pk.w[1]) : "v"(p[2*h][2]),   "v"(p[2*h][3]));   \
            asm("v_cvt_pk_bf16_f32 %0, %1, %2" : "=v"(pk.w[2]) : "v"(p[2*h+1][0]), "v"(p[2*h+1][1])); \
            asm("v_cvt_pk_bf16_f32 %0, %1, %2" : "=v"(pk.w[3]) : "v"(p[2*h+1][2]), "v"(p[2*h+1][3])); \
            lacc = __builtin_amdgcn_mfma_f32_16x16x32_bf16(ones.v, pk.v, lacc, 0, 0, 0); \
            int pbase = ((8 * h + quad) ^ l16) * 4;                              \
            _Pragma("unroll")                                                    \
            for (int dt = 0; dt < 4; dt++) {                                     \
                int drow = dt * 16 + l16;                                        \
                union { u16 s[8]; bf16x8 v; } vk;                                \
                *(uint2*)&vk.s[0] = *(const uint2*)&Vs[b][drow * 64 + pbase];    \
                *(uint2*)&vk.s[4] = *(const uint2*)&Vs[b][drow * 64 + (pbase ^ 16)]; \
                Oacc[dt] = __builtin_amdgcn_mfma_f32_16x16x32_bf16(vk.v, pk.v, Oacc[dt], 0, 0, 0); \
            }                                                                    \
        }                                                                        \
        __builtin_amdgcn_s_setprio(0);                                           \
    }

    // main: unrolled x2 so V reg sets alternate with no copies
    for (int ii = 0; ii < 7; ii++) {
        ATT_STEP(2 * ii,     1, 1, vB, 1, vA)      // write V(i+1)=vA, load V(i+2)->vB
        ATT_STEP(2 * ii + 1, 1, 1, vA, 1, vB)
    }
    ATT_STEP(14, 1, 0, vB, 1, vA)                  // K(15) only; write V(15)=vA
    ATT_STEP(15, 0, 0, vA, 0, vB)                  // drain & compute last tile
    #undef ATT_STEP

    {
        float rl = __builtin_amdgcn_rcpf(lacc[0]);   // l for col q=l16 (rows identical)
        #pragma unroll
        for (int dt = 0; dt < 4; dt++) {
            union { u16 s[4]; uint2 v; } ok;
            #pragma unroll
            for (int r = 0; r < 4; r++) ok.s[r] = f2bf(Oacc[dt][r] * rl);
            *(uint2*)&QO[qoff + dt * 16 + quad * 4] = ok.v;
        }
    }
}

// -------- out-proj GEMM: 128m x 64n tiles, 768 blocks (3.0/CU balanced), BK=64 --------
// (A/B under test: this is the only non-R4 kernel in this submission.)
__global__ __launch_bounds__(256) void gemm_out(
    const u16* __restrict__ Qg, const u16* __restrict__ Bt,
    const float* __restrict__ bias, float* __restrict__ out)
{
    const int K = 768;
    __shared__ __align__(16) u16 As[2][128 * 64];   // 16 KB each
    __shared__ __align__(16) u16 Bs[2][64 * 64];    // 8 KB each  (total 48 KB)

    int tid = threadIdx.x;
    int lane = tid & 63, wave = tid >> 6;
    int quad = lane >> 4, l16 = lane & 15;
    int wm = wave >> 1, wn = wave & 1;               // wave tile: 64m x 32n
    int id = blockIdx.x;
    int xcd = id & 7, j = id >> 3;                   // j in [0,96)
    int m0 = (((j & 7) << 3) + xcd) * 128;           // 64 m-tiles, XCD-pinned
    int n0 = (j >> 3) * 64;                          // 12 n-tiles

    f32x4 acc[4][2];
    #pragma unroll
    for (int i = 0; i < 4; i++)
        #pragma unroll
        for (int jj = 0; jj < 2; jj++) acc[i][jj] = (f32x4){0.f, 0.f, 0.f, 0.f};

    int r0 = tid >> 3, cg = tid & 7;
    int g = cg ^ (r0 & 7);
    const u16* GA[4]; const u16* GB[2];
    #pragma unroll
    for (int it = 0; it < 4; it++) {
        int m = m0 + it * 32 + r0, b = m >> 10, npos = m & 1023;
        GA[it] = Qg + (((size_t)(b * 12) * 1024 + npos) << 6) + g * 8;  // + h*65536
    }
    #pragma unroll
    for (int it = 0; it < 2; it++)
        GB[it] = Bt + (size_t)(n0 + it * 32 + r0) * K + g * 8;          // + kt

    #define STAGE_OUT(i2, b)                                              \
        _Pragma("unroll")                                                 \
        for (int it = 0; it < 4; it++)                                    \
            cp16(GA[it] + (size_t)(i2) * 65536, &As[b][(it * 256 + tid) * 8]); \
        _Pragma("unroll")                                                 \
        for (int it = 0; it < 2; it++)                                    \
            cp16(GB[it] + (i2) * 64,            &Bs[b][(it * 256 + tid) * 8]);

    STAGE_OUT(0, 0)
    for (int i = 0; i < 12; i++) {
        int b = i & 1;
        if (i + 1 < 12) {
            STAGE_OUT(i + 1, b ^ 1)
            asm volatile("s_waitcnt vmcnt(6)" ::: "memory");
        } else {
            asm volatile("s_waitcnt vmcnt(0)" ::: "memory");
        }
        __builtin_amdgcn_s_barrier();
        bf16x8 af[2][4], bfr[2][2];
        #pragma unroll
        for (int ko = 0; ko < 2; ko++) {
            #pragma unroll
            for (int x = 0; x < 4; x++) {
                int Ra = wm * 64 + x * 16 + l16;
                af[ko][x]  = *(const bf16x8*)&As[b][Ra * 64 + (((ko * 4 + quad) ^ (Ra & 7)) * 8)];
            }
            #pragma unroll
            for (int y = 0; y < 2; y++) {
                int Rb = wn * 32 + y * 16 + l16;
                bfr[ko][y] = *(const bf16x8*)&Bs[b][Rb * 64 + (((ko * 4 + quad) ^ (Rb & 7)) * 8)];
            }
        }
        #pragma unroll
        for (int ko = 0; ko < 2; ko++)
            #pragma unroll
            for (int x = 0; x < 4; x++)
                #pragma unroll
                for (int y = 0; y < 2; y++)
                    acc[x][y] = __builtin_amdgcn_mfma_f32_16x16x32_bf16(af[ko][x], bfr[ko][y], acc[x][y], 0, 0, 0);
        __builtin_amdgcn_s_barrier();
    }
    #undef STAGE_OUT

    #pragma unroll
    for (int i = 0; i < 4; i++) {
        int mbase = m0 + wm * 64 + i * 16 + quad * 4;
        #pragma unroll
        for (int jj = 0; jj < 2; jj++) {
            int n = n0 + wn * 32 + jj * 16 + l16;
            float bv = bias[n];
            #pragma unroll
            for (int r = 0; r < 4; r++)
                out[(size_t)(mbase + r) * 768 + n] = acc[i][jj][r] + bv;
        }
    }
}

extern "C" void kernel_launch(void* const* d_in, const int* in_sizes, int n_in,
                              void* d_out, int out_size, void* d_ws, size_t ws_size,
                              hipStream_t stream) {
    const float* x     = (const float*)d_in[0];   // [8,1024,768] f32
    const float* w_qkv = (const float*)d_in[1];   // [768,2304] f32
    const float* w_out = (const float*)d_in[2];   // [768,768] f32
    const float* b_out = (const float*)d_in[3];   // [768] f32
    float* out = (float*)d_out;                   // [8,1024,768] f32

    char* ws = (char*)d_ws;
    u16* wtq  = (u16*)(ws);                   // [2304][768] bf16    3,538,944 B
    u16* wto  = (u16*)(ws + 3538944);         // [768][768]  bf16    1,179,648 B
    u16* Qbuf = (u16*)(ws + 4718592);         // [8,12,1024,64] bf16 12,582,912 B
    u16* xbf  = (u16*)(ws + 17301504);        // [8192][768] bf16    12,582,912 B  (29.9 MB)
    // K natural [b,h,n,64] and V TRANSPOSED [b,h,64,n] live in d_out (2x12.58 MB);
    // both fully consumed by attn128 before gemm_out overwrites d_out.
    u16* Kbuf = (u16*)d_out;
    u16* Vbuf = (u16*)d_out + 6291456;

    prep<<<dim3(5376), 256, 0, stream>>>(x, w_qkv, w_out, xbf, wtq, wto);
    gemm_qkv<<<dim3(1152), 256, 0, stream>>>(xbf, wtq, Qbuf, Kbuf, Vbuf);
    attn128<<<dim3(768), 512, 0, stream>>>(Qbuf, Kbuf, Vbuf);
    gemm_out<<<dim3(768), 256, 0, stream>>>(Qbuf, wto, b_out, out);
}